// Round 9
// baseline (722.405 us; speedup 1.0000x reference)
//
#include <hip/hip_runtime.h>
#include <hip/hip_bf16.h>

#define NN 50000
#define EE 400000
#define EP 450000   // EE + NN self-loops

typedef __attribute__((ext_vector_type(8))) short short8;
typedef __attribute__((ext_vector_type(4))) float f32x4;

__device__ __forceinline__ float bf2f(__hip_bfloat16 b) { return __bfloat162float(b); }
__device__ __forceinline__ float us2f(unsigned short u) {
    unsigned int x = ((unsigned int)u) << 16;
    union { unsigned int i; float f; } c; c.i = x; return c.f;
}

// ---------------------------------------------------------------------------
// prep A: W1/W2 f32->bf16 + zero deg/cursor (contiguous 2N ints)
// ---------------------------------------------------------------------------
__global__ void prep_cvt(const float* __restrict__ W1, const float* __restrict__ W2,
                         __hip_bfloat16* __restrict__ w1b, __hip_bfloat16* __restrict__ w2b,
                         int* __restrict__ degz) {
    int gid = blockIdx.x * blockDim.x + threadIdx.x;
    int nth = gridDim.x * blockDim.x;
    for (int i = gid; i < 131072; i += nth) {
        if (i < 65536) w1b[i] = __float2bfloat16(W1[i]);
        else w2b[i - 65536] = __float2bfloat16(W2[i - 65536]);
    }
    for (int i = gid; i < 2 * NN; i += nth) degz[i] = 0;
}

// ---------------------------------------------------------------------------
// prep B: u1 = W1^T a1 (4 heads x 128), u2 = W2^T a2 (4 heads x 512).
// ---------------------------------------------------------------------------
__global__ void prep_u(const float* __restrict__ W1, const float* __restrict__ a1s, const float* __restrict__ a1d,
                       const float* __restrict__ W2, const float* __restrict__ a2s, const float* __restrict__ a2d,
                       float* __restrict__ u1s, float* __restrict__ u1d,
                       float* __restrict__ u2s, float* __restrict__ u2d) {
    int t = threadIdx.x;
    if (blockIdx.x == 0) {
        int h = t >> 7, k = t & 127;
        float s = 0.f, d = 0.f;
        for (int c = 0; c < 128; c++) {
            float w = W1[(size_t)(h * 128 + c) * 128 + k];
            s += a1s[h * 128 + c] * w;
            d += a1d[h * 128 + c] * w;
        }
        u1s[t] = s; u1d[t] = d;
    } else {
        int idx = (blockIdx.x - 1) * 512 + t;   // 0..2047
        int h = idx >> 9, k = idx & 511;
        float s = 0.f, d = 0.f;
        for (int c = 0; c < 32; c++) {
            float w = W2[(size_t)(h * 32 + c) * 512 + k];
            s += a2s[h * 32 + c] * w;
            d += a2d[h * 32 + c] * w;
        }
        u2s[idx] = s; u2d[idx] = d;
    }
}

// ---------------------------------------------------------------------------
// sdx: one wave per node. x row f32 -> xb bf16; s1/d1 = x . u1 (4 heads).
// ---------------------------------------------------------------------------
__global__ void sdx_kernel(const float* __restrict__ x,
                           const float* __restrict__ u1s, const float* __restrict__ u1d,
                           __hip_bfloat16* __restrict__ xb,
                           float* __restrict__ s1, float* __restrict__ d1) {
    int n = blockIdx.x * 4 + (threadIdx.x >> 6);
    int l = threadIdx.x & 63;
    float2 xv = *(const float2*)(x + (size_t)n * 128 + 2 * l);
    __hip_bfloat16* xbp = xb + (size_t)n * 128 + 2 * l;
    xbp[0] = __float2bfloat16(xv.x);
    xbp[1] = __float2bfloat16(xv.y);
    float sp[4], dp[4];
#pragma unroll
    for (int h = 0; h < 4; h++) {
        sp[h] = xv.x * u1s[h * 128 + 2 * l] + xv.y * u1s[h * 128 + 2 * l + 1];
        dp[h] = xv.x * u1d[h * 128 + 2 * l] + xv.y * u1d[h * 128 + 2 * l + 1];
    }
#pragma unroll
    for (int m = 1; m <= 32; m <<= 1)
#pragma unroll
        for (int h = 0; h < 4; h++) {
            sp[h] += __shfl_xor(sp[h], m, 64);
            dp[h] += __shfl_xor(dp[h], m, 64);
        }
    if (l == 0)
#pragma unroll
        for (int h = 0; h < 4; h++) { s1[n * 4 + h] = sp[h]; d1[n * 4 + h] = dp[h]; }
}

// ---------------------------------------------------------------------------
// CSR build (proven)
// ---------------------------------------------------------------------------
__global__ void deg_kernel(const int* __restrict__ ei, int* __restrict__ deg) {
    int e = blockIdx.x * blockDim.x + threadIdx.x;
    if (e >= EP) return;
    int dst = (e < EE) ? ei[EE + e] : e - EE;
    atomicAdd(&deg[dst], 1);
}

#define SCAN_T 1024
__global__ void scan_kernel(const int* __restrict__ deg, int* __restrict__ offsets) {
    __shared__ int part[SCAN_T];
    int t = threadIdx.x;
    constexpr int CH = (NN + SCAN_T - 1) / SCAN_T;
    int lo = t * CH;
    int hi = lo + CH; if (hi > NN) hi = NN;
    int s = 0;
    for (int i = lo; i < hi && i < NN; i++) s += deg[i];
    part[t] = s;
    __syncthreads();
    for (int off = 1; off < SCAN_T; off <<= 1) {
        int v = (t >= off) ? part[t - off] : 0;
        __syncthreads();
        part[t] += v;
        __syncthreads();
    }
    int run = (t == 0) ? 0 : part[t - 1];
    for (int i = lo; i < hi && i < NN; i++) { offsets[i] = run; run += deg[i]; }
    if (t == SCAN_T - 1) offsets[NN] = run;
}

__global__ void fill_kernel(const int* __restrict__ ei, const int* __restrict__ offsets,
                            int* __restrict__ cursor, int* __restrict__ elist) {
    int e = blockIdx.x * blockDim.x + threadIdx.x;
    if (e >= EP) return;
    int src, dst;
    if (e < EE) { src = ei[e]; dst = ei[EE + e]; } else { src = dst = e - EE; }
    int pos = atomicAdd(&cursor[dst], 1);
    elist[offsets[dst] + pos] = src;
}

// ---------------------------------------------------------------------------
// gather_agg: per-head aggregation in INPUT space (128 ch):
// agg[n, h*128+c] = sum_e w_e^h * xb[src_e, c];  den1[n,h] = sum_e w_e^h.
// ---------------------------------------------------------------------------
__global__ void gather_agg(const int* __restrict__ elist, const int* __restrict__ offsets,
                           const __hip_bfloat16* __restrict__ xb,
                           const float* __restrict__ s1, const float* __restrict__ d1,
                           __hip_bfloat16* __restrict__ agg, float* __restrict__ den1) {
    int gid = blockIdx.x * blockDim.x + threadIdx.x;
    if (gid >= NN * 64) return;
    int node = gid >> 6, t = gid & 63;
    int hh = t >> 4, ci0 = (t & 15) * 8;
    int j0 = offsets[node], j1 = offsets[node + 1];
    float dv = d1[node * 4 + hh];
    float den = 0.f, acc[8] = {0, 0, 0, 0, 0, 0, 0, 0};
    const unsigned short* hb = (const unsigned short*)xb;
    for (int j = j0; j < j1; j++) {
        int src = elist[j];
        float xx = s1[src * 4 + hh] + dv;
        xx = xx > 0.f ? xx : 0.2f * xx;
        float w = __expf(xx);
        den += w;
        const unsigned short* hp = hb + (size_t)src * 128 + ci0;
        ushort4 a = *(const ushort4*)hp;
        ushort4 b = *(const ushort4*)(hp + 4);
        acc[0] += w * us2f(a.x); acc[1] += w * us2f(a.y);
        acc[2] += w * us2f(a.z); acc[3] += w * us2f(a.w);
        acc[4] += w * us2f(b.x); acc[5] += w * us2f(b.y);
        acc[6] += w * us2f(b.z); acc[7] += w * us2f(b.w);
    }
    __hip_bfloat16* op = agg + (size_t)node * 512 + hh * 128 + ci0;
#pragma unroll
    for (int c = 0; c < 8; c++) op[c] = __float2bfloat16(acc[c]);
    if ((t & 15) == 0) den1[node * 4 + hh] = den;
}

// ---------------------------------------------------------------------------
// gemm_l1: act1[n, h*128+co] = elu( (agg . W1_h)/den1 + b1 ), plus s2/d2
// epilogue via u2. Head loop fully unrolled -> afrag indices STATIC (4 frags
// live = 16 VGPRs; the R8 version's dynamic head*4+kk indexing spilled
// afrag[16] to scratch: VGPR=52, WRITE 129MB, 159 µs).
// ---------------------------------------------------------------------------
__global__ __launch_bounds__(256, 2)
void gemm_l1(const __hip_bfloat16* __restrict__ agg,
             const __hip_bfloat16* __restrict__ w1b,
             const float* __restrict__ den1, const float* __restrict__ b1,
             const float* __restrict__ u2s, const float* __restrict__ u2d,
             __hip_bfloat16* __restrict__ act1,
             float* __restrict__ s2, float* __restrict__ d2) {
    int wave = threadIdx.x >> 6, lane = threadIdx.x & 63;
    int m0 = blockIdx.x * 64 + wave * 16;
    int r = lane & 15, quad = lane >> 4;
    int am = m0 + r; if (am >= NN) am = NN - 1;
    const __hip_bfloat16* arow = agg + (size_t)am * 512 + quad * 8;
    const __hip_bfloat16* wrow = w1b + (size_t)r * 128 + quad * 8;
    float s2a[4][4] = {}, d2a[4][4] = {};
#pragma unroll
    for (int head = 0; head < 4; head++) {
        short8 afrag[4];
#pragma unroll
        for (int kk = 0; kk < 4; kk++) afrag[kk] = *(const short8*)(arow + head * 128 + kk * 32);
        float invd[4];
#pragma unroll
        for (int i = 0; i < 4; i++) {
            int m = m0 + quad * 4 + i; if (m >= NN) m = NN - 1;
            invd[i] = 1.0f / den1[m * 4 + head];
        }
#pragma unroll
        for (int t = 0; t < 8; t++) {
            int n0 = head * 128 + t * 16;
            f32x4 acc = {0.f, 0.f, 0.f, 0.f};
#pragma unroll
            for (int kk = 0; kk < 4; kk++) {
                short8 b = *(const short8*)(wrow + (size_t)n0 * 128 + kk * 32);
                acc = __builtin_amdgcn_mfma_f32_16x16x32_bf16(afrag[kk], b, acc, 0, 0, 0);
            }
            float b1v = b1[n0 + r];
            float us[4], ud[4];
#pragma unroll
            for (int h2 = 0; h2 < 4; h2++) {
                us[h2] = u2s[h2 * 512 + n0 + r];
                ud[h2] = u2d[h2 * 512 + n0 + r];
            }
#pragma unroll
            for (int i = 0; i < 4; i++) {
                float val = acc[i] * invd[i] + b1v;
                val = val > 0.f ? val : (__expf(val) - 1.0f);
                int m = m0 + quad * 4 + i;
                if (m < NN) act1[(size_t)m * 512 + n0 + r] = __float2bfloat16(val);
#pragma unroll
                for (int h2 = 0; h2 < 4; h2++) { s2a[i][h2] += val * us[h2]; d2a[i][h2] += val * ud[h2]; }
            }
        }
    }
#pragma unroll
    for (int mask = 1; mask <= 8; mask <<= 1)
#pragma unroll
        for (int i = 0; i < 4; i++)
#pragma unroll
            for (int h2 = 0; h2 < 4; h2++) {
                s2a[i][h2] += __shfl_xor(s2a[i][h2], mask, 64);
                d2a[i][h2] += __shfl_xor(d2a[i][h2], mask, 64);
            }
    if (r == 0)
#pragma unroll
        for (int i = 0; i < 4; i++) {
            int m = m0 + quad * 4 + i;
            if (m < NN)
#pragma unroll
                for (int h2 = 0; h2 < 4; h2++) { s2[m * 4 + h2] = s2a[i][h2]; d2[m * 4 + h2] = d2a[i][h2]; }
        }
}

// ---------------------------------------------------------------------------
// gemm_l2: h2[n,co] = act1[n,:] . W2[co,:] (K=512, NO=128). launch_bounds
// (256,2) gives the allocator the full 256-VGPR budget for afrag[16]=64 regs.
// ---------------------------------------------------------------------------
__global__ __launch_bounds__(256, 2)
void gemm_l2(const __hip_bfloat16* __restrict__ act1,
             const __hip_bfloat16* __restrict__ w2b,
             __hip_bfloat16* __restrict__ h2) {
    int wave = threadIdx.x >> 6, lane = threadIdx.x & 63;
    int m0 = blockIdx.x * 64 + wave * 16;
    int r = lane & 15, quad = lane >> 4;
    int am = m0 + r; if (am >= NN) am = NN - 1;
    short8 afrag[16];
    const __hip_bfloat16* arow = act1 + (size_t)am * 512 + quad * 8;
#pragma unroll
    for (int kk = 0; kk < 16; kk++) afrag[kk] = *(const short8*)(arow + kk * 32);
    const __hip_bfloat16* wrow = w2b + (size_t)r * 512 + quad * 8;
#pragma unroll
    for (int n0 = 0; n0 < 128; n0 += 16) {
        f32x4 acc = {0.f, 0.f, 0.f, 0.f};
#pragma unroll
        for (int kk = 0; kk < 16; kk++) {
            short8 b = *(const short8*)(wrow + (size_t)n0 * 512 + kk * 32);
            acc = __builtin_amdgcn_mfma_f32_16x16x32_bf16(afrag[kk], b, acc, 0, 0, 0);
        }
#pragma unroll
        for (int i = 0; i < 4; i++) {
            int m = m0 + quad * 4 + i;
            if (m < NN) h2[(size_t)m * 128 + n0 + r] = __float2bfloat16(acc[i]);
        }
    }
}

// ---------------------------------------------------------------------------
// gather2f: wave/node over h2 (2 ch/lane) + fused layer-3 GEMM + s3/d3.
// ---------------------------------------------------------------------------
__global__ void gather2f(const int* __restrict__ elist, const int* __restrict__ offsets,
                         const __hip_bfloat16* __restrict__ h2,
                         const float* __restrict__ s2, const float* __restrict__ d2,
                         const float* __restrict__ b2, const float* __restrict__ W3,
                         const float* __restrict__ a3s, const float* __restrict__ a3d,
                         __hip_bfloat16* __restrict__ h3,
                         float* __restrict__ s3, float* __restrict__ d3) {
    int node = (blockIdx.x * 256 + threadIdx.x) >> 6;
    if (node >= NN) return;
    int lane = threadIdx.x & 63;
    int c0 = 2 * lane, hh = lane >> 4;
    float w3a[8], w3b[8], as3[8], ad3[8];
#pragma unroll
    for (int c = 0; c < 8; c++) {
        w3a[c] = W3[c * 128 + c0]; w3b[c] = W3[c * 128 + c0 + 1];
        as3[c] = a3s[c]; ad3[c] = a3d[c];
    }
    float bb0 = b2[c0], bb1 = b2[c0 + 1];
    const unsigned short* hb = (const unsigned short*)h2;
    int j0 = offsets[node], j1 = offsets[node + 1];
    float dv = d2[node * 4 + hh];
    float den = 0.f, a0 = 0.f, a1 = 0.f;
    for (int j = j0; j < j1; j++) {
        int src = elist[j];
        float xx = s2[src * 4 + hh] + dv;
        xx = xx > 0.f ? xx : 0.2f * xx;
        float w = __expf(xx);
        den += w;
        ushort2 hv = *(const ushort2*)(hb + (size_t)src * 128 + c0);
        a0 += w * us2f(hv.x);
        a1 += w * us2f(hv.y);
    }
    float inv = 1.0f / den;
    a0 = a0 * inv + bb0; a0 = a0 > 0.f ? a0 : (__expf(a0) - 1.0f);
    a1 = a1 * inv + bb1; a1 = a1 > 0.f ? a1 : (__expf(a1) - 1.0f);
    float pc[8], s3p = 0.f, d3p = 0.f;
#pragma unroll
    for (int c = 0; c < 8; c++) {
        pc[c] = a0 * w3a[c] + a1 * w3b[c];
        s3p += pc[c] * as3[c];
        d3p += pc[c] * ad3[c];
    }
#pragma unroll
    for (int mask = 1; mask <= 32; mask <<= 1) {
#pragma unroll
        for (int c = 0; c < 8; c++) pc[c] += __shfl_xor(pc[c], mask, 64);
        s3p += __shfl_xor(s3p, mask, 64);
        d3p += __shfl_xor(d3p, mask, 64);
    }
    if (lane == 0) {
#pragma unroll
        for (int c = 0; c < 8; c++) h3[node * 8 + c] = __float2bfloat16(pc[c]);
        s3[node] = s3p;
        d3[node] = d3p;
    }
}

// ---------------------------------------------------------------------------
// gather3: thread/node over h3 (8 ch) -> act3
// ---------------------------------------------------------------------------
__global__ void gather3(const int* __restrict__ elist, const int* __restrict__ offsets,
                        const __hip_bfloat16* __restrict__ h3,
                        const float* __restrict__ s3, const float* __restrict__ d3,
                        const float* __restrict__ b3, __hip_bfloat16* __restrict__ act3) {
    int node = blockIdx.x * blockDim.x + threadIdx.x;
    if (node >= NN) return;
    const unsigned short* h3b = (const unsigned short*)h3;
    int j0 = offsets[node], j1 = offsets[node + 1];
    float dv = d3[node];
    float den = 0.f, acc[8] = {0, 0, 0, 0, 0, 0, 0, 0};
    for (int j = j0; j < j1; j++) {
        int src = elist[j];
        float xx = s3[src] + dv;
        xx = xx > 0.f ? xx : 0.2f * xx;
        float w = __expf(xx);
        den += w;
        ushort4 q0 = *(const ushort4*)(h3b + src * 8);
        ushort4 q1 = *(const ushort4*)(h3b + src * 8 + 4);
        acc[0] += w * us2f(q0.x); acc[1] += w * us2f(q0.y);
        acc[2] += w * us2f(q0.z); acc[3] += w * us2f(q0.w);
        acc[4] += w * us2f(q1.x); acc[5] += w * us2f(q1.y);
        acc[6] += w * us2f(q1.z); acc[7] += w * us2f(q1.w);
    }
    float inv = 1.0f / den;
#pragma unroll
    for (int c = 0; c < 8; c++) {
        float v = acc[c] * inv + b3[c];
        v = v > 0.f ? v : (__expf(v) - 1.0f);
        act3[node * 8 + c] = __float2bfloat16(v);
    }
}

// ---------------------------------------------------------------------------
// Final edge MLP
// ---------------------------------------------------------------------------
__global__ void mlp_kernel(const int* __restrict__ ei,
                           const __hip_bfloat16* __restrict__ act3,
                           const float* __restrict__ ea, const float* __restrict__ yr,
                           const float* __restrict__ qt,
                           const float* __restrict__ fc1w, const float* __restrict__ fc1b,
                           const float* __restrict__ fc2w, const float* __restrict__ fc2b,
                           float* __restrict__ outp) {
    __shared__ float w1[16 * 19], b1s[16], w2[16];
    for (int i = threadIdx.x; i < 16 * 19; i += blockDim.x) w1[i] = fc1w[i];
    if (threadIdx.x < 16) {
        b1s[threadIdx.x] = fc1b[threadIdx.x];
        w2[threadIdx.x] = fc2w[threadIdx.x];
    }
    __syncthreads();
    int e = blockIdx.x * blockDim.x + threadIdx.x;
    if (e >= EE) return;
    int src = ei[e], dst = ei[EE + e];
    float z[19];
#pragma unroll
    for (int i = 0; i < 8; i++) z[i] = bf2f(act3[src * 8 + i]);
#pragma unroll
    for (int i = 0; i < 8; i++) z[8 + i] = bf2f(act3[dst * 8 + i]);
    z[16] = ea[e]; z[17] = yr[e]; z[18] = qt[e];
    float acc2 = fc2b[0];
#pragma unroll
    for (int j = 0; j < 16; j++) {
        float a = b1s[j];
#pragma unroll
        for (int i = 0; i < 19; i++) a += z[i] * w1[j * 19 + i];
        a = a > 0.f ? a : 0.f;
        acc2 += a * w2[j];
    }
    outp[e] = acc2;
}

// ---------------------------------------------------------------------------
extern "C" void kernel_launch(void* const* d_in, const int* in_sizes, int n_in,
                              void* d_out, int out_size, void* d_ws, size_t ws_size,
                              hipStream_t stream) {
    const float* x    = (const float*)d_in[0];
    const int*   ei   = (const int*)d_in[1];
    const float* ea   = (const float*)d_in[2];
    const float* yr   = (const float*)d_in[3];
    const float* qt   = (const float*)d_in[4];
    const float* W1   = (const float*)d_in[5];
    const float* a1s  = (const float*)d_in[6];
    const float* a1d  = (const float*)d_in[7];
    const float* b1   = (const float*)d_in[8];
    const float* W2   = (const float*)d_in[9];
    const float* a2s  = (const float*)d_in[10];
    const float* a2d  = (const float*)d_in[11];
    const float* b2   = (const float*)d_in[12];
    const float* W3   = (const float*)d_in[13];
    const float* a3s  = (const float*)d_in[14];
    const float* a3d  = (const float*)d_in[15];
    const float* b3   = (const float*)d_in[16];
    const float* fc1w = (const float*)d_in[17];
    const float* fc1b = (const float*)d_in[18];
    const float* fc2w = (const float*)d_in[19];
    const float* fc2b = (const float*)d_in[20];
    float* outp = (float*)d_out;

    char* ws = (char*)d_ws;
    __hip_bfloat16* xb   = (__hip_bfloat16*)(ws);                    // N*128 bf16 (12.8 MB)
    __hip_bfloat16* agg  = (__hip_bfloat16*)(ws + 12800000);         // N*512 bf16 (51.2 MB)
    __hip_bfloat16* act1 = (__hip_bfloat16*)(ws + 64000000);         // N*512 bf16 (51.2 MB)
    __hip_bfloat16* h2   = (__hip_bfloat16*)(ws + 115200000);        // N*128 bf16 (12.8 MB)
    float* s1   = (float*)(ws + 128000000);                          // N*4
    float* d1   = (float*)(ws + 128800000);                          // N*4
    float* den1 = (float*)(ws + 129600000);                          // N*4
    float* s2   = (float*)(ws + 130400000);                          // N*4
    float* d2   = (float*)(ws + 131200000);                          // N*4
    float* s3   = (float*)(ws + 132000000);                          // N
    float* d3   = (float*)(ws + 132200000);                          // N
    int*   deg    = (int*)(ws + 132400000);                          // N
    int*   cursor = (int*)(ws + 132600000);                          // N (contiguous)
    int*   offsets= (int*)(ws + 132800000);                          // N+1
    int*   elist  = (int*)(ws + 133000016);                          // EP
    __hip_bfloat16* w1b = (__hip_bfloat16*)(ws + 134800016);         // 512*128
    __hip_bfloat16* w2b = (__hip_bfloat16*)(ws + 134931088);         // 128*512
    float* u1s = (float*)(ws + 135062160);                           // 512
    float* u1d = (float*)(ws + 135064208);                           // 512
    float* u2s = (float*)(ws + 135066256);                           // 2048
    float* u2d = (float*)(ws + 135074448);                           // 2048
    __hip_bfloat16* h3   = (__hip_bfloat16*)(ws + 135082640);        // N*8
    __hip_bfloat16* act3 = (__hip_bfloat16*)(ws + 135882640);        // N*8

    // ---- prep ----
    prep_cvt<<<512, 256, 0, stream>>>(W1, W2, w1b, w2b, deg);
    prep_u<<<5, 512, 0, stream>>>(W1, a1s, a1d, W2, a2s, a2d, u1s, u1d, u2s, u2d);
    sdx_kernel<<<12500, 256, 0, stream>>>(x, u1s, u1d, xb, s1, d1);

    // ---- CSR ----
    deg_kernel<<<(EP + 255) / 256, 256, 0, stream>>>(ei, deg);
    scan_kernel<<<1, SCAN_T, 0, stream>>>(deg, offsets);
    fill_kernel<<<(EP + 255) / 256, 256, 0, stream>>>(ei, offsets, cursor, elist);

    // ---- Layer 1: aggregate in x-space, then project ----
    gather_agg<<<12500, 256, 0, stream>>>(elist, offsets, xb, s1, d1, agg, den1);
    gemm_l1<<<(NN + 63) / 64, 256, 0, stream>>>(agg, w1b, den1, b1, u2s, u2d, act1, s2, d2);

    // ---- Layer 2: project, then gather (+ fused layer-3 GEMM) ----
    gemm_l2<<<(NN + 63) / 64, 256, 0, stream>>>(act1, w2b, h2);
    gather2f<<<12500, 256, 0, stream>>>(elist, offsets, h2, s2, d2, b2, W3, a3s, a3d, h3, s3, d3);

    // ---- Layer 3 gather ----
    gather3<<<(NN + 255) / 256, 256, 0, stream>>>(elist, offsets, h3, s3, d3, b3, act3);

    // ---- Final edge MLP ----
    mlp_kernel<<<(EE + 255) / 256, 256, 0, stream>>>(ei, act3, ea, yr, qt,
                                                     fc1w, fc1b, fc2w, fc2b, outp);
}

// Round 10
// 616.745 us; speedup vs baseline: 1.1713x; 1.1713x over previous
//
#include <hip/hip_runtime.h>
#include <hip/hip_bf16.h>

#define NN 50000
#define EE 400000
#define EP 450000   // EE + NN self-loops

typedef __attribute__((ext_vector_type(8))) short short8;
typedef __attribute__((ext_vector_type(4))) float f32x4;

__device__ __forceinline__ float bf2f(__hip_bfloat16 b) { return __bfloat162float(b); }
__device__ __forceinline__ float us2f(unsigned short u) {
    unsigned int x = ((unsigned int)u) << 16;
    union { unsigned int i; float f; } c; c.i = x; return c.f;
}

// ---------------------------------------------------------------------------
// prep A: W1/W2 f32->bf16 + zero deg/cursor (contiguous 2N ints)
// ---------------------------------------------------------------------------
__global__ void prep_cvt(const float* __restrict__ W1, const float* __restrict__ W2,
                         __hip_bfloat16* __restrict__ w1b, __hip_bfloat16* __restrict__ w2b,
                         int* __restrict__ degz) {
    int gid = blockIdx.x * blockDim.x + threadIdx.x;
    int nth = gridDim.x * blockDim.x;
    for (int i = gid; i < 131072; i += nth) {
        if (i < 65536) w1b[i] = __float2bfloat16(W1[i]);
        else w2b[i - 65536] = __float2bfloat16(W2[i - 65536]);
    }
    for (int i = gid; i < 2 * NN; i += nth) degz[i] = 0;
}

// ---------------------------------------------------------------------------
// prep B: u1 = W1^T a1 (4 heads x 128), u2 = W2^T a2 (4 heads x 512).
// ---------------------------------------------------------------------------
__global__ void prep_u(const float* __restrict__ W1, const float* __restrict__ a1s, const float* __restrict__ a1d,
                       const float* __restrict__ W2, const float* __restrict__ a2s, const float* __restrict__ a2d,
                       float* __restrict__ u1s, float* __restrict__ u1d,
                       float* __restrict__ u2s, float* __restrict__ u2d) {
    int t = threadIdx.x;
    if (blockIdx.x == 0) {
        int h = t >> 7, k = t & 127;
        float s = 0.f, d = 0.f;
        for (int c = 0; c < 128; c++) {
            float w = W1[(size_t)(h * 128 + c) * 128 + k];
            s += a1s[h * 128 + c] * w;
            d += a1d[h * 128 + c] * w;
        }
        u1s[t] = s; u1d[t] = d;
    } else {
        int idx = (blockIdx.x - 1) * 512 + t;   // 0..2047
        int h = idx >> 9, k = idx & 511;
        float s = 0.f, d = 0.f;
        for (int c = 0; c < 32; c++) {
            float w = W2[(size_t)(h * 32 + c) * 512 + k];
            s += a2s[h * 32 + c] * w;
            d += a2d[h * 32 + c] * w;
        }
        u2s[idx] = s; u2d[idx] = d;
    }
}

// ---------------------------------------------------------------------------
// sdx: one wave per node. x row f32 -> xb bf16; s1/d1 = x . u1 (4 heads).
// ---------------------------------------------------------------------------
__global__ void sdx_kernel(const float* __restrict__ x,
                           const float* __restrict__ u1s, const float* __restrict__ u1d,
                           __hip_bfloat16* __restrict__ xb,
                           float* __restrict__ s1, float* __restrict__ d1) {
    int n = blockIdx.x * 4 + (threadIdx.x >> 6);
    int l = threadIdx.x & 63;
    float2 xv = *(const float2*)(x + (size_t)n * 128 + 2 * l);
    __hip_bfloat16* xbp = xb + (size_t)n * 128 + 2 * l;
    xbp[0] = __float2bfloat16(xv.x);
    xbp[1] = __float2bfloat16(xv.y);
    float sp[4], dp[4];
#pragma unroll
    for (int h = 0; h < 4; h++) {
        sp[h] = xv.x * u1s[h * 128 + 2 * l] + xv.y * u1s[h * 128 + 2 * l + 1];
        dp[h] = xv.x * u1d[h * 128 + 2 * l] + xv.y * u1d[h * 128 + 2 * l + 1];
    }
#pragma unroll
    for (int m = 1; m <= 32; m <<= 1)
#pragma unroll
        for (int h = 0; h < 4; h++) {
            sp[h] += __shfl_xor(sp[h], m, 64);
            dp[h] += __shfl_xor(dp[h], m, 64);
        }
    if (l == 0)
#pragma unroll
        for (int h = 0; h < 4; h++) { s1[n * 4 + h] = sp[h]; d1[n * 4 + h] = dp[h]; }
}

// ---------------------------------------------------------------------------
// CSR build (proven)
// ---------------------------------------------------------------------------
__global__ void deg_kernel(const int* __restrict__ ei, int* __restrict__ deg) {
    int e = blockIdx.x * blockDim.x + threadIdx.x;
    if (e >= EP) return;
    int dst = (e < EE) ? ei[EE + e] : e - EE;
    atomicAdd(&deg[dst], 1);
}

#define SCAN_T 1024
__global__ void scan_kernel(const int* __restrict__ deg, int* __restrict__ offsets) {
    __shared__ int part[SCAN_T];
    int t = threadIdx.x;
    constexpr int CH = (NN + SCAN_T - 1) / SCAN_T;
    int lo = t * CH;
    int hi = lo + CH; if (hi > NN) hi = NN;
    int s = 0;
    for (int i = lo; i < hi && i < NN; i++) s += deg[i];
    part[t] = s;
    __syncthreads();
    for (int off = 1; off < SCAN_T; off <<= 1) {
        int v = (t >= off) ? part[t - off] : 0;
        __syncthreads();
        part[t] += v;
        __syncthreads();
    }
    int run = (t == 0) ? 0 : part[t - 1];
    for (int i = lo; i < hi && i < NN; i++) { offsets[i] = run; run += deg[i]; }
    if (t == SCAN_T - 1) offsets[NN] = run;
}

__global__ void fill_kernel(const int* __restrict__ ei, const int* __restrict__ offsets,
                            int* __restrict__ cursor, int* __restrict__ elist) {
    int e = blockIdx.x * blockDim.x + threadIdx.x;
    if (e >= EP) return;
    int src, dst;
    if (e < EE) { src = ei[e]; dst = ei[EE + e]; } else { src = dst = e - EE; }
    int pos = atomicAdd(&cursor[dst], 1);
    elist[offsets[dst] + pos] = src;
}

// ---------------------------------------------------------------------------
// gather_agg: per-head aggregation in INPUT space (proven; never in top-5):
// agg[n, h*128+c] = sum_e w_e^h * xb[src_e, c];  den1[n,h] = sum_e w_e^h.
// ---------------------------------------------------------------------------
__global__ void gather_agg(const int* __restrict__ elist, const int* __restrict__ offsets,
                           const __hip_bfloat16* __restrict__ xb,
                           const float* __restrict__ s1, const float* __restrict__ d1,
                           __hip_bfloat16* __restrict__ agg, float* __restrict__ den1) {
    int gid = blockIdx.x * blockDim.x + threadIdx.x;
    if (gid >= NN * 64) return;
    int node = gid >> 6, t = gid & 63;
    int hh = t >> 4, ci0 = (t & 15) * 8;
    int j0 = offsets[node], j1 = offsets[node + 1];
    float dv = d1[node * 4 + hh];
    float den = 0.f, acc[8] = {0, 0, 0, 0, 0, 0, 0, 0};
    const unsigned short* hb = (const unsigned short*)xb;
    for (int j = j0; j < j1; j++) {
        int src = elist[j];
        float xx = s1[src * 4 + hh] + dv;
        xx = xx > 0.f ? xx : 0.2f * xx;
        float w = __expf(xx);
        den += w;
        const unsigned short* hp = hb + (size_t)src * 128 + ci0;
        ushort4 a = *(const ushort4*)hp;
        ushort4 b = *(const ushort4*)(hp + 4);
        acc[0] += w * us2f(a.x); acc[1] += w * us2f(a.y);
        acc[2] += w * us2f(a.z); acc[3] += w * us2f(a.w);
        acc[4] += w * us2f(b.x); acc[5] += w * us2f(b.y);
        acc[6] += w * us2f(b.z); acc[7] += w * us2f(b.w);
    }
    __hip_bfloat16* op = agg + (size_t)node * 512 + hh * 128 + ci0;
#pragma unroll
    for (int c = 0; c < 8; c++) op[c] = __float2bfloat16(acc[c]);
    if ((t & 15) == 0) den1[node * 4 + hh] = den;
}

// ---------------------------------------------------------------------------
// gemm_l1 v3: act1[n, h*128+co] = elu( (agg_h . W1_h)/den1 + b1 ).
// Compact runtime n0 loop (R5's proven shape). A-frags RELOADED per tile
// from the wave's own 1KB agg row (L1-hit) -> no afrag array, no dynamic
// indexing, no spill (R8: dynamic idx spilled; R9: full unroll = 6x traffic).
// ---------------------------------------------------------------------------
__global__ __launch_bounds__(256, 4)
void gemm_l1(const __hip_bfloat16* __restrict__ agg,
             const __hip_bfloat16* __restrict__ w1b,
             const float* __restrict__ den1, const float* __restrict__ b1,
             __hip_bfloat16* __restrict__ act1) {
    int wave = threadIdx.x >> 6, lane = threadIdx.x & 63;
    int m0 = blockIdx.x * 64 + wave * 16;
    int r = lane & 15, quad = lane >> 4;
    int am = m0 + r; if (am >= NN) am = NN - 1;
    const __hip_bfloat16* arow = agg + (size_t)am * 512 + quad * 8;
    const __hip_bfloat16* wrow = w1b + (size_t)r * 128 + quad * 8;
    float invd[4];
    for (int n0 = 0; n0 < 512; n0 += 16) {
        int head = n0 >> 7;
        if ((n0 & 127) == 0) {
#pragma unroll
            for (int i = 0; i < 4; i++) {
                int m = m0 + quad * 4 + i; if (m >= NN) m = NN - 1;
                invd[i] = 1.0f / den1[m * 4 + head];
            }
        }
        const __hip_bfloat16* ab = arow + head * 128;
        f32x4 acc = {0.f, 0.f, 0.f, 0.f};
#pragma unroll
        for (int kk = 0; kk < 4; kk++) {
            short8 a = *(const short8*)(ab + kk * 32);
            short8 b = *(const short8*)(wrow + (size_t)n0 * 128 + kk * 32);
            acc = __builtin_amdgcn_mfma_f32_16x16x32_bf16(a, b, acc, 0, 0, 0);
        }
        float b1v = b1[n0 + r];
#pragma unroll
        for (int i = 0; i < 4; i++) {
            float val = acc[i] * invd[i] + b1v;
            val = val > 0.f ? val : (__expf(val) - 1.0f);
            int m = m0 + quad * 4 + i;
            if (m < NN) act1[(size_t)m * 512 + n0 + r] = __float2bfloat16(val);
        }
    }
}

// ---------------------------------------------------------------------------
// sd2: one wave per node. s2/d2[n,h2] = act1[n,:] . u2[h2,:]  (4 heads, K=512)
// 8 ch/lane, butterfly reduce.
// ---------------------------------------------------------------------------
__global__ void sd2_kernel(const __hip_bfloat16* __restrict__ act1,
                           const float* __restrict__ u2s, const float* __restrict__ u2d,
                           float* __restrict__ s2, float* __restrict__ d2) {
    int n = blockIdx.x * 4 + (threadIdx.x >> 6);
    int l = threadIdx.x & 63;
    const unsigned short* ap = (const unsigned short*)act1 + (size_t)n * 512 + l * 8;
    ushort4 q0 = *(const ushort4*)ap;
    ushort4 q1 = *(const ushort4*)(ap + 4);
    float av[8] = { us2f(q0.x), us2f(q0.y), us2f(q0.z), us2f(q0.w),
                    us2f(q1.x), us2f(q1.y), us2f(q1.z), us2f(q1.w) };
    float sp[4], dp[4];
#pragma unroll
    for (int h = 0; h < 4; h++) {
        float ss = 0.f, dd = 0.f;
#pragma unroll
        for (int c = 0; c < 8; c++) {
            ss += av[c] * u2s[h * 512 + l * 8 + c];
            dd += av[c] * u2d[h * 512 + l * 8 + c];
        }
        sp[h] = ss; dp[h] = dd;
    }
#pragma unroll
    for (int m = 1; m <= 32; m <<= 1)
#pragma unroll
        for (int h = 0; h < 4; h++) {
            sp[h] += __shfl_xor(sp[h], m, 64);
            dp[h] += __shfl_xor(dp[h], m, 64);
        }
    if (l == 0)
#pragma unroll
        for (int h = 0; h < 4; h++) { s2[n * 4 + h] = sp[h]; d2[n * 4 + h] = dp[h]; }
}

// ---------------------------------------------------------------------------
// gemm_l2: h2[n,co] = act1[n,:] . W2[co,:] (K=512, NO=128).
// afrag[16]=64 regs static; bounds(256,2) -> 256-reg cap, no spill (R8's
// no-bounds version spilled: VGPR=44). Runtime n0 loop keeps code compact.
// ---------------------------------------------------------------------------
__global__ __launch_bounds__(256, 2)
void gemm_l2(const __hip_bfloat16* __restrict__ act1,
             const __hip_bfloat16* __restrict__ w2b,
             __hip_bfloat16* __restrict__ h2) {
    int wave = threadIdx.x >> 6, lane = threadIdx.x & 63;
    int m0 = blockIdx.x * 64 + wave * 16;
    int r = lane & 15, quad = lane >> 4;
    int am = m0 + r; if (am >= NN) am = NN - 1;
    short8 afrag[16];
    const __hip_bfloat16* arow = act1 + (size_t)am * 512 + quad * 8;
#pragma unroll
    for (int kk = 0; kk < 16; kk++) afrag[kk] = *(const short8*)(arow + kk * 32);
    const __hip_bfloat16* wrow = w2b + (size_t)r * 512 + quad * 8;
    for (int n0 = 0; n0 < 128; n0 += 16) {
        f32x4 acc = {0.f, 0.f, 0.f, 0.f};
#pragma unroll
        for (int kk = 0; kk < 16; kk++) {
            short8 b = *(const short8*)(wrow + (size_t)n0 * 512 + kk * 32);
            acc = __builtin_amdgcn_mfma_f32_16x16x32_bf16(afrag[kk], b, acc, 0, 0, 0);
        }
#pragma unroll
        for (int i = 0; i < 4; i++) {
            int m = m0 + quad * 4 + i;
            if (m < NN) h2[(size_t)m * 128 + n0 + r] = __float2bfloat16(acc[i]);
        }
    }
}

// ---------------------------------------------------------------------------
// gather2f: wave/node over h2 (2 ch/lane) + fused layer-3 GEMM + s3/d3.
// ---------------------------------------------------------------------------
__global__ void gather2f(const int* __restrict__ elist, const int* __restrict__ offsets,
                         const __hip_bfloat16* __restrict__ h2,
                         const float* __restrict__ s2, const float* __restrict__ d2,
                         const float* __restrict__ b2, const float* __restrict__ W3,
                         const float* __restrict__ a3s, const float* __restrict__ a3d,
                         __hip_bfloat16* __restrict__ h3,
                         float* __restrict__ s3, float* __restrict__ d3) {
    int node = (blockIdx.x * 256 + threadIdx.x) >> 6;
    if (node >= NN) return;
    int lane = threadIdx.x & 63;
    int c0 = 2 * lane, hh = lane >> 4;
    float w3a[8], w3b[8], as3[8], ad3[8];
#pragma unroll
    for (int c = 0; c < 8; c++) {
        w3a[c] = W3[c * 128 + c0]; w3b[c] = W3[c * 128 + c0 + 1];
        as3[c] = a3s[c]; ad3[c] = a3d[c];
    }
    float bb0 = b2[c0], bb1 = b2[c0 + 1];
    const unsigned short* hb = (const unsigned short*)h2;
    int j0 = offsets[node], j1 = offsets[node + 1];
    float dv = d2[node * 4 + hh];
    float den = 0.f, a0 = 0.f, a1 = 0.f;
    for (int j = j0; j < j1; j++) {
        int src = elist[j];
        float xx = s2[src * 4 + hh] + dv;
        xx = xx > 0.f ? xx : 0.2f * xx;
        float w = __expf(xx);
        den += w;
        ushort2 hv = *(const ushort2*)(hb + (size_t)src * 128 + c0);
        a0 += w * us2f(hv.x);
        a1 += w * us2f(hv.y);
    }
    float inv = 1.0f / den;
    a0 = a0 * inv + bb0; a0 = a0 > 0.f ? a0 : (__expf(a0) - 1.0f);
    a1 = a1 * inv + bb1; a1 = a1 > 0.f ? a1 : (__expf(a1) - 1.0f);
    float pc[8], s3p = 0.f, d3p = 0.f;
#pragma unroll
    for (int c = 0; c < 8; c++) {
        pc[c] = a0 * w3a[c] + a1 * w3b[c];
        s3p += pc[c] * as3[c];
        d3p += pc[c] * ad3[c];
    }
#pragma unroll
    for (int mask = 1; mask <= 32; mask <<= 1) {
#pragma unroll
        for (int c = 0; c < 8; c++) pc[c] += __shfl_xor(pc[c], mask, 64);
        s3p += __shfl_xor(s3p, mask, 64);
        d3p += __shfl_xor(d3p, mask, 64);
    }
    if (lane == 0) {
#pragma unroll
        for (int c = 0; c < 8; c++) h3[node * 8 + c] = __float2bfloat16(pc[c]);
        s3[node] = s3p;
        d3[node] = d3p;
    }
}

// ---------------------------------------------------------------------------
// gather3: thread/node over h3 (8 ch) -> act3
// ---------------------------------------------------------------------------
__global__ void gather3(const int* __restrict__ elist, const int* __restrict__ offsets,
                        const __hip_bfloat16* __restrict__ h3,
                        const float* __restrict__ s3, const float* __restrict__ d3,
                        const float* __restrict__ b3, __hip_bfloat16* __restrict__ act3) {
    int node = blockIdx.x * blockDim.x + threadIdx.x;
    if (node >= NN) return;
    const unsigned short* h3b = (const unsigned short*)h3;
    int j0 = offsets[node], j1 = offsets[node + 1];
    float dv = d3[node];
    float den = 0.f, acc[8] = {0, 0, 0, 0, 0, 0, 0, 0};
    for (int j = j0; j < j1; j++) {
        int src = elist[j];
        float xx = s3[src] + dv;
        xx = xx > 0.f ? xx : 0.2f * xx;
        float w = __expf(xx);
        den += w;
        ushort4 q0 = *(const ushort4*)(h3b + src * 8);
        ushort4 q1 = *(const ushort4*)(h3b + src * 8 + 4);
        acc[0] += w * us2f(q0.x); acc[1] += w * us2f(q0.y);
        acc[2] += w * us2f(q0.z); acc[3] += w * us2f(q0.w);
        acc[4] += w * us2f(q1.x); acc[5] += w * us2f(q1.y);
        acc[6] += w * us2f(q1.z); acc[7] += w * us2f(q1.w);
    }
    float inv = 1.0f / den;
#pragma unroll
    for (int c = 0; c < 8; c++) {
        float v = acc[c] * inv + b3[c];
        v = v > 0.f ? v : (__expf(v) - 1.0f);
        act3[node * 8 + c] = __float2bfloat16(v);
    }
}

// ---------------------------------------------------------------------------
// Final edge MLP
// ---------------------------------------------------------------------------
__global__ void mlp_kernel(const int* __restrict__ ei,
                           const __hip_bfloat16* __restrict__ act3,
                           const float* __restrict__ ea, const float* __restrict__ yr,
                           const float* __restrict__ qt,
                           const float* __restrict__ fc1w, const float* __restrict__ fc1b,
                           const float* __restrict__ fc2w, const float* __restrict__ fc2b,
                           float* __restrict__ outp) {
    __shared__ float w1[16 * 19], b1s[16], w2[16];
    for (int i = threadIdx.x; i < 16 * 19; i += blockDim.x) w1[i] = fc1w[i];
    if (threadIdx.x < 16) {
        b1s[threadIdx.x] = fc1b[threadIdx.x];
        w2[threadIdx.x] = fc2w[threadIdx.x];
    }
    __syncthreads();
    int e = blockIdx.x * blockDim.x + threadIdx.x;
    if (e >= EE) return;
    int src = ei[e], dst = ei[EE + e];
    float z[19];
#pragma unroll
    for (int i = 0; i < 8; i++) z[i] = bf2f(act3[src * 8 + i]);
#pragma unroll
    for (int i = 0; i < 8; i++) z[8 + i] = bf2f(act3[dst * 8 + i]);
    z[16] = ea[e]; z[17] = yr[e]; z[18] = qt[e];
    float acc2 = fc2b[0];
#pragma unroll
    for (int j = 0; j < 16; j++) {
        float a = b1s[j];
#pragma unroll
        for (int i = 0; i < 19; i++) a += z[i] * w1[j * 19 + i];
        a = a > 0.f ? a : 0.f;
        acc2 += a * w2[j];
    }
    outp[e] = acc2;
}

// ---------------------------------------------------------------------------
extern "C" void kernel_launch(void* const* d_in, const int* in_sizes, int n_in,
                              void* d_out, int out_size, void* d_ws, size_t ws_size,
                              hipStream_t stream) {
    const float* x    = (const float*)d_in[0];
    const int*   ei   = (const int*)d_in[1];
    const float* ea   = (const float*)d_in[2];
    const float* yr   = (const float*)d_in[3];
    const float* qt   = (const float*)d_in[4];
    const float* W1   = (const float*)d_in[5];
    const float* a1s  = (const float*)d_in[6];
    const float* a1d  = (const float*)d_in[7];
    const float* b1   = (const float*)d_in[8];
    const float* W2   = (const float*)d_in[9];
    const float* a2s  = (const float*)d_in[10];
    const float* a2d  = (const float*)d_in[11];
    const float* b2   = (const float*)d_in[12];
    const float* W3   = (const float*)d_in[13];
    const float* a3s  = (const float*)d_in[14];
    const float* a3d  = (const float*)d_in[15];
    const float* b3   = (const float*)d_in[16];
    const float* fc1w = (const float*)d_in[17];
    const float* fc1b = (const float*)d_in[18];
    const float* fc2w = (const float*)d_in[19];
    const float* fc2b = (const float*)d_in[20];
    float* outp = (float*)d_out;

    char* ws = (char*)d_ws;
    __hip_bfloat16* xb   = (__hip_bfloat16*)(ws);                    // N*128 bf16 (12.8 MB)
    __hip_bfloat16* agg  = (__hip_bfloat16*)(ws + 12800000);         // N*512 bf16 (51.2 MB)
    __hip_bfloat16* act1 = (__hip_bfloat16*)(ws + 64000000);         // N*512 bf16 (51.2 MB)
    __hip_bfloat16* h2   = (__hip_bfloat16*)(ws + 115200000);        // N*128 bf16 (12.8 MB)
    float* s1   = (float*)(ws + 128000000);                          // N*4
    float* d1   = (float*)(ws + 128800000);                          // N*4
    float* den1 = (float*)(ws + 129600000);                          // N*4
    float* s2   = (float*)(ws + 130400000);                          // N*4
    float* d2   = (float*)(ws + 131200000);                          // N*4
    float* s3   = (float*)(ws + 132000000);                          // N
    float* d3   = (float*)(ws + 132200000);                          // N
    int*   deg    = (int*)(ws + 132400000);                          // N
    int*   cursor = (int*)(ws + 132600000);                          // N (contiguous)
    int*   offsets= (int*)(ws + 132800000);                          // N+1
    int*   elist  = (int*)(ws + 133000016);                          // EP
    __hip_bfloat16* w1b = (__hip_bfloat16*)(ws + 134800016);         // 512*128
    __hip_bfloat16* w2b = (__hip_bfloat16*)(ws + 134931088);         // 128*512
    float* u1s = (float*)(ws + 135062160);                           // 512
    float* u1d = (float*)(ws + 135064208);                           // 512
    float* u2s = (float*)(ws + 135066256);                           // 2048
    float* u2d = (float*)(ws + 135074448);                           // 2048
    __hip_bfloat16* h3   = (__hip_bfloat16*)(ws + 135082640);        // N*8
    __hip_bfloat16* act3 = (__hip_bfloat16*)(ws + 135882640);        // N*8

    // ---- prep ----
    prep_cvt<<<512, 256, 0, stream>>>(W1, W2, w1b, w2b, deg);
    prep_u<<<5, 512, 0, stream>>>(W1, a1s, a1d, W2, a2s, a2d, u1s, u1d, u2s, u2d);
    sdx_kernel<<<12500, 256, 0, stream>>>(x, u1s, u1d, xb, s1, d1);

    // ---- CSR ----
    deg_kernel<<<(EP + 255) / 256, 256, 0, stream>>>(ei, deg);
    scan_kernel<<<1, SCAN_T, 0, stream>>>(deg, offsets);
    fill_kernel<<<(EP + 255) / 256, 256, 0, stream>>>(ei, offsets, cursor, elist);

    // ---- Layer 1: aggregate in x-space, project, then s2/d2 ----
    gather_agg<<<12500, 256, 0, stream>>>(elist, offsets, xb, s1, d1, agg, den1);
    gemm_l1<<<(NN + 63) / 64, 256, 0, stream>>>(agg, w1b, den1, b1, act1);
    sd2_kernel<<<12500, 256, 0, stream>>>(act1, u2s, u2d, s2, d2);

    // ---- Layer 2: project, then gather (+ fused layer-3 GEMM) ----
    gemm_l2<<<(NN + 63) / 64, 256, 0, stream>>>(act1, w2b, h2);
    gather2f<<<12500, 256, 0, stream>>>(elist, offsets, h2, s2, d2, b2, W3, a3s, a3d, h3, s3, d3);

    // ---- Layer 3 gather ----
    gather3<<<(NN + 255) / 256, 256, 0, stream>>>(elist, offsets, h3, s3, d3, b3, act3);

    // ---- Final edge MLP ----
    mlp_kernel<<<(EE + 255) / 256, 256, 0, stream>>>(ei, act3, ea, yr, qt,
                                                     fc1w, fc1b, fc2w, fc2b, outp);
}